// Round 19
// baseline (496.695 us; speedup 1.0000x reference)
//
#include <hip/hip_runtime.h>

#define B_ 8
#define T_ 2048
#define D_ 768
#define H_ 12
#define HS_ 64
#define LN_EPS 1e-5f
#define NC 32   // chunks
#define TC 64   // timesteps per chunk

typedef __attribute__((ext_vector_type(8))) short bf16x8;
typedef __attribute__((ext_vector_type(4))) float f32x4;

__device__ __forceinline__ ushort f2bf(float f) {
  unsigned u = __builtin_bit_cast(unsigned, f);
  unsigned r = (u + 0x7FFFu + ((u >> 16) & 1u)) >> 16;
  return (ushort)r;
}
__device__ __forceinline__ float bf2f(ushort u) {
  return __builtin_bit_cast(float, ((unsigned)u) << 16);
}

// fragment address: element (row t, col i) of a 64x64 tile in MFMA A/B-frag
// layout (m/n = t, k = i). 8 frags x 512 halves.
__device__ __forceinline__ int fragaddr(int t, int i) {
  return ((t >> 4) * 2 + (i >> 5)) * 512 + ((((i >> 3) & 3) * 16) + (t & 15)) * 8 + (i & 7);
}
__device__ __forceinline__ int fragswz(int i) {
  return (((i >> 3) & 3) << 3) ^ (((i >> 5) & 1) << 5);
}

// ---------------- canary ----------------
__global__ __launch_bounds__(256) void zero_out_kernel(float* __restrict__ out, int n) {
  for (int i = blockIdx.x * 256 + threadIdx.x; i < n; i += gridDim.x * 256)
    out[i] = 0.f;
}

// ---------------- fused prep + LayerNorm ----------------
__global__ __launch_bounds__(256) void prepln_kernel(
    const float* __restrict__ x, const float* __restrict__ gamma,
    const float* __restrict__ beta, ushort* __restrict__ xn,
    const float* __restrict__ w0, const float* __restrict__ w1,
    const float* __restrict__ w2, const float* __restrict__ w3,
    const float* __restrict__ w4, const float* __restrict__ Wx,
    ushort* __restrict__ dst, ushort* __restrict__ WxT) {
  __shared__ ushort tile[32][33];
  const int bid = blockIdx.x;
  if (bid < 4096) {
    const int wv = threadIdx.x >> 6;
    const int lane = threadIdx.x & 63;
    const int row = bid * 4 + wv;
    const float* xr = x + (size_t)row * D_;
    float4 a[3];
#pragma unroll
    for (int s = 0; s < 3; ++s)
      a[s] = *reinterpret_cast<const float4*>(xr + s * 256 + lane * 4);
    float sum = 0.f;
#pragma unroll
    for (int s = 0; s < 3; ++s) sum += a[s].x + a[s].y + a[s].z + a[s].w;
#pragma unroll
    for (int off = 32; off; off >>= 1) sum += __shfl_xor(sum, off);
    float mu = sum * (1.f / 768.f);
    float vs = 0.f;
#pragma unroll
    for (int s = 0; s < 3; ++s) {
      float dx = a[s].x - mu, dy = a[s].y - mu, dz = a[s].z - mu, dw = a[s].w - mu;
      vs += dx * dx + dy * dy + dz * dz + dw * dw;
    }
#pragma unroll
    for (int off = 32; off; off >>= 1) vs += __shfl_xor(vs, off);
    float rs = rsqrtf(vs * (1.f / 768.f) + LN_EPS);
    ushort* orow = xn + (size_t)row * D_;
#pragma unroll
    for (int s = 0; s < 3; ++s) {
      int col = s * 256 + lane * 4;
      float4 g = *reinterpret_cast<const float4*>(gamma + col);
      float4 bb = *reinterpret_cast<const float4*>(beta + col);
      ushort4 o;
      o.x = f2bf((a[s].x - mu) * rs * g.x + bb.x);
      o.y = f2bf((a[s].y - mu) * rs * g.y + bb.y);
      o.z = f2bf((a[s].z - mu) * rs * g.z + bb.z);
      o.w = f2bf((a[s].w - mu) * rs * g.w + bb.w);
      *reinterpret_cast<ushort4*>(orow + col) = o;
    }
  } else if (bid < 4672) {
    const float* srcs[5] = {w0, w1, w2, w3, w4};
    const int slots[5] = {0, 1, 2, 4, 5};
    int idx = ((bid - 4096) * 256 + threadIdx.x) * 4;
#pragma unroll
    for (int s = 0; s < 5; ++s) {
      float4 v = *reinterpret_cast<const float4*>(srcs[s] + idx);
      ushort4 o;
      o.x = f2bf(v.x); o.y = f2bf(v.y); o.z = f2bf(v.z); o.w = f2bf(v.w);
      *reinterpret_cast<ushort4*>(dst + (size_t)slots[s] * 589824 + idx) = o;
    }
  } else {
    const int q = bid - 4672;
    const int bx = (q % 24) * 32;
    const int by = (q / 24) * 32;
    const int tx = threadIdx.x & 31, ty = threadIdx.x >> 5;
#pragma unroll
    for (int r = 0; r < 32; r += 8)
      tile[ty + r][tx] = f2bf(Wx[(size_t)(by + ty + r) * 768 + bx + tx]);
    __syncthreads();
#pragma unroll
    for (int r = 0; r < 32; r += 8)
      WxT[(size_t)(bx + ty + r) * 768 + by + tx] = tile[tx][ty + r];
  }
}

// ---------------- 256x256 BK=32 wide-wave-tile bf16 MFMA GEMM ----------------
// C[m,n] = sum_k A[m,k]*W[n,k].  K=768 = 24 tiles. 256 threads = 4 waves (2x2),
// wave tile 128x128 (8x8 frags, acc=256 VGPR -> launch_bounds(256,1), 1 wave/SIMD).
// FLOP per LDS byte = 64 (vs 32 at 64x64) -> LDS-BW ceiling ~60% MfmaUtil.
// Triple-buffered (96 KiB), prefetch distance 2, vmcnt: steady 16, tail 8->0.
// modes: 0 fp32 plain
//        5 cat -> sel0: d0 k bf16 row-major | sel1: d1 v FRAG tiles
//                 sel2: d2 r sigmoid thread-tiles | sel3: d3 z bf16 row-major
__global__ __launch_bounds__(256, 1) void gemm_w(
    const ushort* __restrict__ A, const ushort* __restrict__ W,
    float* __restrict__ Cf,
    ushort* __restrict__ d0, ushort* __restrict__ d1,
    ushort* __restrict__ d2, ushort* __restrict__ d3, int mode) {
  __shared__ __align__(16) ushort lds[49152];  // A: 3x8192, B: 3x8192 (96 KiB)
  const int tid = threadIdx.x;
  const int wid = tid >> 6;
  const int lane = tid & 63;
  const int wr = wid >> 1, wc = wid & 1;
  const int fr = lane & 15, fq = lane >> 4;
  const int m0 = blockIdx.x * 256, n0 = blockIdx.y * 256;
  const int rseg = fq ^ ((fr >> 1) & 3);  // swizzled read seg (r16-verified)

  // staging maps: load l in 0..3; g = l*256+tid; row = g>>2; src seg inverse-swz
  size_t offA[4], offB[4];
#pragma unroll
  for (int l = 0; l < 4; ++l) {
    int g = l * 256 + tid;
    int row = g >> 2;
    int seg = (g & 3) ^ ((row >> 1) & 3);
    offA[l] = (size_t)(m0 + row) * 768 + seg * 8;
    offB[l] = (size_t)(n0 + row) * 768 + seg * 8;
  }

  f32x4 acc[8][8];
#pragma unroll
  for (int m = 0; m < 8; ++m)
#pragma unroll
    for (int n = 0; n < 8; ++n) acc[m][n] = (f32x4){0.f, 0.f, 0.f, 0.f};

#define STAGE_T(kk0, b)                                                           \
  {                                                                               \
    _Pragma("unroll") for (int l = 0; l < 4; ++l) {                               \
      __builtin_amdgcn_global_load_lds(                                           \
          (const __attribute__((address_space(1))) void*)(A + offA[l] + (kk0)),   \
          (__attribute__((address_space(3))) void*)(lds + (b) * 8192 + l * 2048 + tid * 8), \
          16, 0, 0);                                                              \
    }                                                                             \
    _Pragma("unroll") for (int l = 0; l < 4; ++l) {                               \
      __builtin_amdgcn_global_load_lds(                                           \
          (const __attribute__((address_space(1))) void*)(W + offB[l] + (kk0)),   \
          (__attribute__((address_space(3))) void*)(lds + 24576 + (b) * 8192 +    \
                                                    l * 2048 + tid * 8),          \
          16, 0, 0);                                                              \
    }                                                                             \
  }

  // prologue: tiles 0, 1, 2
  STAGE_T(0, 0);
  STAGE_T(32, 1);
  STAGE_T(64, 2);
  asm volatile("s_waitcnt vmcnt(16)" ::: "memory");  // tile 0 landed
  __builtin_amdgcn_s_barrier();

#pragma unroll 3
  for (int t = 0; t < 24; ++t) {
    const int buf = t % 3;
    bf16x8 bF[8];
#pragma unroll
    for (int nf = 0; nf < 8; ++nf)
      bF[nf] = *reinterpret_cast<const bf16x8*>(
          lds + 24576 + buf * 8192 + (wc * 128 + nf * 16 + fr) * 32 + rseg * 8);
    __builtin_amdgcn_s_setprio(1);
#pragma unroll
    for (int mi = 0; mi < 8; ++mi) {
      bf16x8 aF = *reinterpret_cast<const bf16x8*>(
          lds + buf * 8192 + (wr * 128 + mi * 16 + fr) * 32 + rseg * 8);
#pragma unroll
      for (int nf = 0; nf < 8; ++nf)
        acc[mi][nf] = __builtin_amdgcn_mfma_f32_16x16x32_bf16(
            aF, bF[nf], acc[mi][nf], 0, 0, 0);
    }
    __builtin_amdgcn_s_setprio(0);
    __builtin_amdgcn_s_barrier();           // all waves consumed buf
    if (t + 3 < 24) {
      STAGE_T((t + 3) * 32, buf);
      asm volatile("s_waitcnt vmcnt(16)" ::: "memory");  // tile t+1 landed
    } else if (t == 21) {
      asm volatile("s_waitcnt vmcnt(8)" ::: "memory");   // tile 22 landed
    } else if (t == 22) {
      asm volatile("s_waitcnt vmcnt(0)" ::: "memory");   // tile 23 landed
    }
    __builtin_amdgcn_s_barrier();
  }
#undef STAGE_T

  // ---- epilogue ----
  const int r0 = fq * 4;
  if (mode == 5) {
    const int sel = n0 >= 2304 ? 3 : n0 >= 1536 ? 2 : n0 >= 768 ? 1 : 0;
    const int nb = n0 - sel * 768;
    if (sel == 1) {
#pragma unroll
      for (int mf = 0; mf < 8; ++mf)
#pragma unroll
        for (int nf = 0; nf < 8; ++nf) {
          int gr = m0 + wr * 128 + mf * 16 + r0;
          int gc = nb + wc * 128 + nf * 16 + fr;
          int b = gr >> 11, t = gr & 2047;
          int c = t >> 6, s0 = t & 63;
          int h = gc >> 6, j = gc & 63;
          size_t addr = ((size_t)((b * 12 + h) * 32 + c)) * 4096 +
                        (size_t)(((j >> 4) * 2 + (s0 >> 5)) * 512 +
                                 (((s0 >> 3) & 3) * 16 + (j & 15)) * 8 + (s0 & 7));
          ushort4 o;
          o.x = f2bf(acc[mf][nf][0]); o.y = f2bf(acc[mf][nf][1]);
          o.z = f2bf(acc[mf][nf][2]); o.w = f2bf(acc[mf][nf][3]);
          *reinterpret_cast<ushort4*>(d1 + addr) = o;
        }
    } else if (sel == 2) {
#pragma unroll
      for (int mf = 0; mf < 8; ++mf)
#pragma unroll
        for (int nf = 0; nf < 8; ++nf) {
          int gr = m0 + wr * 128 + mf * 16 + r0;
          int gc = nb + wc * 128 + nf * 16 + fr;
          int b = gr >> 11, t = gr & 2047;
          int c = t >> 6, tin = t & 63;
          int h = gc >> 6, j = gc & 63;
          size_t addr = ((size_t)((b * 12 + h) * 32 + c)) * 4096 +
                        (size_t)(((tin >> 4) * 64 + ((tin >> 2) & 3) * 16 + (j & 15)) * 16 +
                                 (j >> 4) * 4);
          ushort4 o;
          o.x = f2bf(1.f / (1.f + __expf(-acc[mf][nf][0])));
          o.y = f2bf(1.f / (1.f + __expf(-acc[mf][nf][1])));
          o.z = f2bf(1.f / (1.f + __expf(-acc[mf][nf][2])));
          o.w = f2bf(1.f / (1.f + __expf(-acc[mf][nf][3])));
          *reinterpret_cast<ushort4*>(d2 + addr) = o;
        }
    } else {
      ushort* dst = sel == 0 ? d0 : d3;
#pragma unroll
      for (int mf = 0; mf < 8; ++mf)
#pragma unroll
        for (int nf = 0; nf < 8; ++nf) {
          int gr = m0 + wr * 128 + mf * 16 + r0;
          int gc = nb + wc * 128 + nf * 16 + fr;
#pragma unroll
          for (int rr = 0; rr < 4; ++rr)
            dst[(size_t)(gr + rr) * 768 + gc] = f2bf(acc[mf][nf][rr]);
        }
    }
  } else {
#pragma unroll
    for (int mf = 0; mf < 8; ++mf)
#pragma unroll
      for (int nf = 0; nf < 8; ++nf) {
        int gr = m0 + wr * 128 + mf * 16 + r0;
        int gc = n0 + wc * 128 + nf * 16 + fr;
#pragma unroll
        for (int rr = 0; rr < 4; ++rr)
          Cf[(size_t)(gr + rr) * 768 + gc] = acc[mf][nf][rr];
      }
  }
}

// ---------------- scan P: per (bh,c): cumprod + Mc = kIA^T V (parallel) ------
__global__ __launch_bounds__(256) void scan_mc3(
    const ushort* __restrict__ kb, const ushort* __restrict__ zb,
    const ushort* __restrict__ vbF, const float* __restrict__ bwp,
    ushort* __restrict__ McT, float* __restrict__ aend) {
  __shared__ ushort kt[64 * 72];
  __shared__ ushort zt[64 * 72];
  __shared__ ushort kIAfA[4096];
  __shared__ float part[256];
  const int bh = blockIdx.x, c = blockIdx.y;
  const int b = bh / H_, h = bh % H_;
  const int tid = threadIdx.x;
  const int w = tid >> 6, lane = tid & 63;
  const int fr = lane & 15, fq = lane >> 4;
  const int row = tid >> 2, c16 = (tid & 3) * 16;
  const float bwh = bwp[h * 64];

  {
    const ushort* gk = kb + ((size_t)(b * T_ + c * TC + row)) * 768 + h * 64 + c16;
    const ushort* gz = zb + ((size_t)(b * T_ + c * TC + row)) * 768 + h * 64 + c16;
    uint4 k0 = *(const uint4*)gk, k1 = *(const uint4*)(gk + 8);
    uint4 z0 = *(const uint4*)gz, z1 = *(const uint4*)(gz + 8);
    *reinterpret_cast<uint4*>(&kt[row * 72 + c16]) = k0;
    *reinterpret_cast<uint4*>(&kt[row * 72 + c16 + 8]) = k1;
    *reinterpret_cast<uint4*>(&zt[row * 72 + c16]) = z0;
    *reinterpret_cast<uint4*>(&zt[row * 72 + c16 + 8]) = z1;
  }
  bf16x8 vfr[8];
  {
    const ushort* vch = vbF + ((size_t)bh * NC + c) * 4096;
#pragma unroll
    for (int f = 0; f < 8; ++f)
      vfr[f] = *reinterpret_cast<const bf16x8*>(vch + f * 512 + lane * 8);
  }
  __syncthreads();
  float dreg[16];
  float p = 1.f;
#pragma unroll
  for (int tt = 0; tt < 16; ++tt) {
    float z = bf2f(zt[(w * 16 + tt) * 72 + lane]);
    float d = 1.f / (1.f + __expf(z + bwh));
    dreg[tt] = d;
    p *= d;
  }
  part[w * 64 + lane] = p;
  __syncthreads();
  float a = 1.f;
  for (int w2 = 0; w2 < w; ++w2) a *= part[w2 * 64 + lane];
  if (w == 0)
    aend[((size_t)bh * NC + c) * 64 + lane] =
        part[lane] * part[64 + lane] * part[128 + lane] * part[192 + lane];
#pragma unroll
  for (int tt = 0; tt < 16; ++tt) {
    int t = w * 16 + tt;
    float k = bf2f(kt[t * 72 + lane]);
    a *= dreg[tt];
    kIAfA[fragaddr(lane, t)] = f2bf(k / a);  // A-frag (m=i, k=s)
  }
  __syncthreads();

  bf16x8 af2[2];
#pragma unroll
  for (int kk = 0; kk < 2; ++kk)
    af2[kk] = *reinterpret_cast<const bf16x8*>(&kIAfA[(w * 2 + kk) * 512 + lane * 8]);
  f32x4 accM[4];
#pragma unroll
  for (int nf = 0; nf < 4; ++nf) accM[nf] = (f32x4){0.f, 0.f, 0.f, 0.f};
#pragma unroll
  for (int kk = 0; kk < 2; ++kk)
#pragma unroll
    for (int nf = 0; nf < 4; ++nf)
      accM[nf] = __builtin_amdgcn_mfma_f32_16x16x32_bf16(af2[kk], vfr[nf * 2 + kk], accM[nf], 0, 0, 0);
  ushort* mch = McT + ((size_t)bh * NC + c) * 4096;
#pragma unroll
  for (int nf = 0; nf < 4; ++nf) {
    ushort4 o;
    o.x = f2bf(accM[nf][0]); o.y = f2bf(accM[nf][1]);
    o.z = f2bf(accM[nf][2]); o.w = f2bf(accM[nf][3]);
    *reinterpret_cast<ushort4*>(&mch[(nf * 16 + fr) * 64 + w * 16 + fq * 4]) = o;
  }
}

// ---------------- scan C: chain, prefetch distance 2 (96x2 blocks) -----------
__global__ __launch_bounds__(256) void scan_chain3(
    const ushort* __restrict__ McT, const float* __restrict__ aend,
    ushort* __restrict__ S0F) {
  const int bh = blockIdx.x;
  const int j = threadIdx.x >> 2;
  const int i0 = blockIdx.y * 32 + (threadIdx.x & 3) * 8;
  const int fbase = ((j >> 4) * 2 + (i0 >> 5)) * 512 + (((i0 >> 3) & 3) * 16 + (j & 15)) * 8;
  const ushort* mbase = McT + ((size_t)bh * NC) * 4096 + j * 64 + i0;
  const float* abase = aend + ((size_t)bh * NC) * 64 + i0;
  float S[8];
#pragma unroll
  for (int p = 0; p < 8; ++p) S[p] = 0.f;

  ushort4 m0 = *reinterpret_cast<const ushort4*>(mbase);
  ushort4 m1 = *reinterpret_cast<const ushort4*>(mbase + 4);
  float4 a0 = *(const float4*)(abase);
  float4 a1 = *(const float4*)(abase + 4);
  ushort4 n0 = *reinterpret_cast<const ushort4*>(mbase + 4096);
  ushort4 n1 = *reinterpret_cast<const ushort4*>(mbase + 4096 + 4);
  float4 b0 = *(const float4*)(abase + 64);
  float4 b1 = *(const float4*)(abase + 64 + 4);

  for (int c = 0; c < NC; ++c) {
    int cn2 = c + 2 < NC ? c + 2 : NC - 1;
    ushort4 p0 = *reinterpret_cast<const ushort4*>(mbase + (size_t)cn2 * 4096);
    ushort4 p1 = *reinterpret_cast<const ushort4*>(mbase + (size_t)cn2 * 4096 + 4);
    float4 q0 = *(const float4*)(abase + (size_t)cn2 * 64);
    float4 q1 = *(const float4*)(abase + (size_t)cn2 * 64 + 4);

    ushort* s0 = S0F + ((size_t)bh * NC + c) * 4096 + fbase;
    ushort4 o0, o1;
    o0.x = f2bf(S[0]); o0.y = f2bf(S[1]); o0.z = f2bf(S[2]); o0.w = f2bf(S[3]);
    o1.x = f2bf(S[4]); o1.y = f2bf(S[5]); o1.z = f2bf(S[6]); o1.w = f2bf(S[7]);
    *reinterpret_cast<ushort4*>(s0) = o0;
    *reinterpret_cast<ushort4*>(s0 + 4) = o1;

    S[0] = a0.x * (S[0] + bf2f(m0.x));
    S[1] = a0.y * (S[1] + bf2f(m0.y));
    S[2] = a0.z * (S[2] + bf2f(m0.z));
    S[3] = a0.w * (S[3] + bf2f(m0.w));
    S[4] = a1.x * (S[4] + bf2f(m1.x));
    S[5] = a1.y * (S[5] + bf2f(m1.y));
    S[6] = a1.z * (S[6] + bf2f(m1.z));
    S[7] = a1.w * (S[7] + bf2f(m1.w));

    m0 = n0; m1 = n1; a0 = b0; a1 = b1;
    n0 = p0; n1 = p1; b0 = q0; b1 = q1;
  }
}

// ---------------- scan Y: per (bh,c): A = causal(kA.kIA^T); y = kA.S0F + A.V --
__global__ __launch_bounds__(256, 2) void scan_y3(
    const ushort* __restrict__ kb, const ushort* __restrict__ zb,
    const ushort* __restrict__ vbF, const ushort* __restrict__ rbF,
    const ushort* __restrict__ S0F, const float* __restrict__ bwp,
    ushort* __restrict__ yrow) {
  __shared__ ushort kt[64 * 72];
  __shared__ ushort zt[64 * 72];
  __shared__ ushort kAf[4096];
  __shared__ ushort kIAfB[4096];
  __shared__ ushort Am[64 * 72];
  __shared__ float part[256];
  const int bh = blockIdx.x, c = blockIdx.y;
  const int b = bh / H_, h = bh % H_;
  const int tid = threadIdx.x;
  const int w = tid >> 6, lane = tid & 63;
  const int fr = lane & 15, fq = lane >> 4;
  const int row = tid >> 2, c16 = (tid & 3) * 16;
  const float bwh = bwp[h * 64];
  const int swz = fragswz(lane);

  {
    const ushort* gk = kb + ((size_t)(b * T_ + c * TC + row)) * 768 + h * 64 + c16;
    const ushort* gz = zb + ((size_t)(b * T_ + c * TC + row)) * 768 + h * 64 + c16;
    uint4 k0 = *(const uint4*)gk, k1 = *(const uint4*)(gk + 8);
    uint4 z0 = *(const uint4*)gz, z1 = *(const uint4*)(gz + 8);
    *reinterpret_cast<uint4*>(&kt[row * 72 + c16]) = k0;
    *reinterpret_cast<uint4*>(&kt[row * 72 + c16 + 8]) = k1;
    *reinterpret_cast<uint4*>(&zt[row * 72 + c16]) = z0;
    *reinterpret_cast<uint4*>(&zt[row * 72 + c16 + 8]) = z1;
  }
  bf16x8 vfr[8], s0fr[8];
  {
    const ushort* vch = vbF + ((size_t)bh * NC + c) * 4096;
    const ushort* s0ch = S0F + ((size_t)bh * NC + c) * 4096;
#pragma unroll
    for (int f = 0; f < 8; ++f) {
      vfr[f] = *reinterpret_cast<const bf16x8*>(vch + f * 512 + lane * 8);
      s0fr[f] = *reinterpret_cast<const bf16x8*>(s0ch + f * 512 + lane * 8);
    }
  }
  ushort4 rp0, rp1, rp2, rp3;
  {
    const ushort* rch = rbF + ((size_t)bh * NC + c) * 4096 + tid * 16;
    rp0 = *reinterpret_cast<const ushort4*>(rch);
    rp1 = *reinterpret_cast<const ushort4*>(rch + 4);
    rp2 = *reinterpret_cast<const ushort4*>(rch + 8);
    rp3 = *reinterpret_cast<const ushort4*>(rch + 12);
  }
  const ushort rl[16] = {rp0.x, rp0.y, rp0.z, rp0.w, rp1.x, rp1.y, rp1.z, rp1.w,
                         rp2.x, rp2.y, rp2.z, rp2.w, rp3.x, rp3.y, rp3.z, rp3.w};
  __syncthreads();
  float dreg[16];
  float p = 1.f;
#pragma unroll
  for (int tt = 0; tt < 16; ++tt) {
    float z = bf2f(zt[(w * 16 + tt) * 72 + lane]);
    float d = 1.f / (1.f + __expf(z + bwh));
    dreg[tt] = d;
    p *= d;
  }
  part[w * 64 + lane] = p;
  __syncthreads();
  float a = 1.f;
  for (int w2 = 0; w2 < w; ++w2) a *= part[w2 * 64 + lane];
#pragma unroll
  for (int tt = 0; tt < 16; ++tt) {
    int t = w * 16 + tt;
    float k = bf2f(kt[t * 72 + lane]);
    a *= dreg[tt];
    int ad = fragaddr(t, lane) ^ swz;
    kAf[ad] = f2bf(k * a);
    kIAfB[ad] = f2bf(k / a);
  }
  __syncthreads();

  bf16x8 af[2];
#pragma unroll
  for (int kk = 0; kk < 2; ++kk) {
    int ra = ((w * 2 + kk) * 512 + lane * 8) ^ (((lane >> 4) << 3) ^ (kk << 5));
    af[kk] = *reinterpret_cast<const bf16x8*>(&kAf[ra]);
  }
  {
    f32x4 accA[4];
#pragma unroll
    for (int nf = 0; nf < 4; ++nf) accA[nf] = (f32x4){0.f, 0.f, 0.f, 0.f};
#pragma unroll
    for (int kk = 0; kk < 2; ++kk)
#pragma unroll
      for (int nf = 0; nf < 4; ++nf) {
        int rb8 = ((nf * 2 + kk) * 512 + lane * 8) ^ (((lane >> 4) << 3) ^ (kk << 5));
        bf16x8 b8 = *reinterpret_cast<const bf16x8*>(&kIAfB[rb8]);
        accA[nf] = __builtin_amdgcn_mfma_f32_16x16x32_bf16(af[kk], b8, accA[nf], 0, 0, 0);
      }
#pragma unroll
    for (int nf = 0; nf < 4; ++nf)
#pragma unroll
      for (int q = 0; q < 4; ++q) {
        int t = w * 16 + fq * 4 + q;
        int s = nf * 16 + fr;
        Am[t * 72 + s] = f2bf((s <= t) ? accA[nf][q] : 0.f);
      }
  }
  __syncthreads();

  f32x4 accY[4];
#pragma unroll
  for (int nf = 0; nf < 4; ++nf) accY[nf] = (f32x4){0.f, 0.f, 0.f, 0.f};
#pragma unroll
  for (int kk = 0; kk < 2; ++kk)
#pragma unroll
    for (int nf = 0; nf < 4; ++nf)
      accY[nf] = __builtin_amdgcn_mfma_f32_16x16x32_bf16(af[kk], s0fr[nf * 2 + kk], accY[nf], 0, 0, 0);
#pragma unroll
  for (int kk = 0; kk < 2; ++kk) {
    bf16x8 am8 = *reinterpret_cast<const bf16x8*>(&Am[(w * 16 + fr) * 72 + kk * 32 + fq * 8]);
#pragma unroll
    for (int nf = 0; nf < 4; ++nf)
      accY[nf] = __builtin_amdgcn_mfma_f32_16x16x32_bf16(am8, vfr[nf * 2 + kk], accY[nf], 0, 0, 0);
  }
#pragma unroll
  for (int nf = 0; nf < 4; ++nf)
#pragma unroll
    for (int q = 0; q < 4; ++q) {
      int t = w * 16 + fq * 4 + q;
      int j = nf * 16 + fr;
      size_t go = ((size_t)(b * T_ + c * TC + t)) * 768 + h * 64 + j;
      yrow[go] = f2bf(accY[nf][q] * bf2f(rl[nf * 4 + q]));
    }
}

// ---------------- launch ----------------
extern "C" void kernel_launch(void* const* d_in, const int* in_sizes, int n_in,
                              void* d_out, int out_size, void* d_ws, size_t ws_size,
                              hipStream_t stream) {
  const float* x     = (const float*)d_in[0];
  const float* Wx    = (const float*)d_in[1];
  const float* Ww    = (const float*)d_in[2];
  const float* bw    = (const float*)d_in[3];
  const float* Wk    = (const float*)d_in[4];
  const float* Wv    = (const float*)d_in[5];
  const float* Wr    = (const float*)d_in[6];
  const float* Wo    = (const float*)d_in[7];
  const float* gamma = (const float*)d_in[8];
  const float* beta  = (const float*)d_in[9];
  float* out = (float*)d_out;

  // workspace (bytes), NEED proven rounds 3-18:
  //   xn   [0,          25165824)  bf16 xn -> McT (after cat)
  //   wb   [25165824,   32243712)  6 slots: Wk,Wv,Wr,M,Wo,Ww
  //   WxT  [32243712,   57409536)  WxT (dead after M-gemm) -> S0F
  //   kb   [57409536,   82575360)
  //   vbF  [82575360,  107741184)  v fragment tiles per (bh,c)
  //   rbF  [107741184, 132907008)  r thread-ordered tiles per (bh,c)
  //   yr   [132907008, 158072832)  head = aend fp32 (dead before scan_y3 writes)
  //   zb   [158072832, 183238656)  bf16 z
  const size_t NEED = 208404480ull;
  if (ws_size < NEED) {
    zero_out_kernel<<<2048, 256, 0, stream>>>(out, out_size);
    return;
  }

  char* ws = (char*)d_ws;
  ushort* xn  = (ushort*)ws;
  ushort* wb  = (ushort*)(ws + 25165824);
  ushort* WxT = (ushort*)(ws + 32243712);
  ushort* kb  = (ushort*)(ws + 57409536);
  ushort* vbF = (ushort*)(ws + 82575360);
  ushort* rbF = (ushort*)(ws + 107741184);
  ushort* yr  = (ushort*)(ws + 132907008);
  ushort* zb  = (ushort*)(ws + 158072832);
  ushort* McT = (ushort*)ws;                 // aliases xn (dead after cat)
  ushort* S0F = (ushort*)(ws + 32243712);    // aliases WxT (dead after M-gemm)
  float*  aendb = (float*)(ws + 132907008);  // yr head (dead before scan_y3)

  ushort* WcatB = wb;                 // slots 0..3: Wk, Wv, Wr, M
  ushort* Mb  = wb + 3 * 589824;
  ushort* WoB = wb + 4 * 589824;
  ushort* WwB = wb + 5 * 589824;

  // fused prep (5 casts + WxT transpose) + LayerNorm
  prepln_kernel<<<5248, 256, 0, stream>>>(x, gamma, beta, xn,
                                          Wk, Wv, Wr, Wo, Ww, Wx, wb, WxT);
  // composite M = Ww @ Wx
  gemm_w<<<dim3(3, 3), 256, 0, stream>>>(WwB, WxT, nullptr, Mb, nullptr, nullptr,
                                         nullptr, 5);
  // fused k/v/r/z GEMM (N=3072): k bf16, v frag, r thread-tiles sigmoid, z bf16
  gemm_w<<<dim3(64, 12), 256, 0, stream>>>(xn, WcatB, nullptr, kb, vbF, rbF, zb, 5);

  scan_mc3<<<dim3(96, NC), 256, 0, stream>>>(kb, zb, vbF, bw, McT, aendb);
  scan_chain3<<<dim3(96, 2), 256, 0, stream>>>(McT, aendb, S0F);
  scan_y3<<<dim3(96, NC), 256, 0, stream>>>(kb, zb, vbF, rbF, S0F, bw, yr);

  // final GEMM (N=768): fp32 out
  gemm_w<<<dim3(64, 3), 256, 0, stream>>>(yr, WoB, out, nullptr, nullptr, nullptr,
                                          nullptr, 0);
}

// Round 20
// 223.452 us; speedup vs baseline: 2.2228x; 2.2228x over previous
//
#include <hip/hip_runtime.h>

#define B_ 8
#define T_ 2048
#define D_ 768
#define H_ 12
#define HS_ 64
#define LN_EPS 1e-5f
#define NC 32   // chunks
#define TC 64   // timesteps per chunk

typedef __attribute__((ext_vector_type(8))) short bf16x8;
typedef __attribute__((ext_vector_type(4))) float f32x4;

__device__ __forceinline__ ushort f2bf(float f) {
  unsigned u = __builtin_bit_cast(unsigned, f);
  unsigned r = (u + 0x7FFFu + ((u >> 16) & 1u)) >> 16;
  return (ushort)r;
}
__device__ __forceinline__ float bf2f(ushort u) {
  return __builtin_bit_cast(float, ((unsigned)u) << 16);
}

// fragment address: element (row t, col i) of a 64x64 tile in MFMA A/B-frag
// layout (m/n = t, k = i). 8 frags x 512 halves.
__device__ __forceinline__ int fragaddr(int t, int i) {
  return ((t >> 4) * 2 + (i >> 5)) * 512 + ((((i >> 3) & 3) * 16) + (t & 15)) * 8 + (i & 7);
}
__device__ __forceinline__ int fragswz(int i) {
  return (((i >> 3) & 3) << 3) ^ (((i >> 5) & 1) << 5);
}

// ---------------- canary ----------------
__global__ __launch_bounds__(256) void zero_out_kernel(float* __restrict__ out, int n) {
  for (int i = blockIdx.x * 256 + threadIdx.x; i < n; i += gridDim.x * 256)
    out[i] = 0.f;
}

// ---------------- fused prep + LayerNorm ----------------
// grid 5248: [0,4096) LN (4 rows each); [4096,4672) 5-way weight cast;
// [4672,5248) WxT transpose. All branches independent.
__global__ __launch_bounds__(256) void prepln_kernel(
    const float* __restrict__ x, const float* __restrict__ gamma,
    const float* __restrict__ beta, ushort* __restrict__ xn,
    const float* __restrict__ w0, const float* __restrict__ w1,
    const float* __restrict__ w2, const float* __restrict__ w3,
    const float* __restrict__ w4, const float* __restrict__ Wx,
    ushort* __restrict__ dst, ushort* __restrict__ WxT) {
  __shared__ ushort tile[32][33];
  const int bid = blockIdx.x;
  if (bid < 4096) {
    const int wv = threadIdx.x >> 6;
    const int lane = threadIdx.x & 63;
    const int row = bid * 4 + wv;
    const float* xr = x + (size_t)row * D_;
    float4 a[3];
#pragma unroll
    for (int s = 0; s < 3; ++s)
      a[s] = *reinterpret_cast<const float4*>(xr + s * 256 + lane * 4);
    float sum = 0.f;
#pragma unroll
    for (int s = 0; s < 3; ++s) sum += a[s].x + a[s].y + a[s].z + a[s].w;
#pragma unroll
    for (int off = 32; off; off >>= 1) sum += __shfl_xor(sum, off);
    float mu = sum * (1.f / 768.f);
    float vs = 0.f;
#pragma unroll
    for (int s = 0; s < 3; ++s) {
      float dx = a[s].x - mu, dy = a[s].y - mu, dz = a[s].z - mu, dw = a[s].w - mu;
      vs += dx * dx + dy * dy + dz * dz + dw * dw;
    }
#pragma unroll
    for (int off = 32; off; off >>= 1) vs += __shfl_xor(vs, off);
    float rs = rsqrtf(vs * (1.f / 768.f) + LN_EPS);
    ushort* orow = xn + (size_t)row * D_;
#pragma unroll
    for (int s = 0; s < 3; ++s) {
      int col = s * 256 + lane * 4;
      float4 g = *reinterpret_cast<const float4*>(gamma + col);
      float4 bb = *reinterpret_cast<const float4*>(beta + col);
      ushort4 o;
      o.x = f2bf((a[s].x - mu) * rs * g.x + bb.x);
      o.y = f2bf((a[s].y - mu) * rs * g.y + bb.y);
      o.z = f2bf((a[s].z - mu) * rs * g.z + bb.z);
      o.w = f2bf((a[s].w - mu) * rs * g.w + bb.w);
      *reinterpret_cast<ushort4*>(orow + col) = o;
    }
  } else if (bid < 4672) {
    const float* srcs[5] = {w0, w1, w2, w3, w4};
    const int slots[5] = {0, 1, 2, 4, 5};
    int idx = ((bid - 4096) * 256 + threadIdx.x) * 4;
#pragma unroll
    for (int s = 0; s < 5; ++s) {
      float4 v = *reinterpret_cast<const float4*>(srcs[s] + idx);
      ushort4 o;
      o.x = f2bf(v.x); o.y = f2bf(v.y); o.z = f2bf(v.z); o.w = f2bf(v.w);
      *reinterpret_cast<ushort4*>(dst + (size_t)slots[s] * 589824 + idx) = o;
    }
  } else {
    const int q = bid - 4672;
    const int bx = (q % 24) * 32;
    const int by = (q / 24) * 32;
    const int tx = threadIdx.x & 31, ty = threadIdx.x >> 5;
#pragma unroll
    for (int r = 0; r < 32; r += 8)
      tile[ty + r][tx] = f2bf(Wx[(size_t)(by + ty + r) * 768 + bx + tx]);
    __syncthreads();
#pragma unroll
    for (int r = 0; r < 32; r += 8)
      WxT[(size_t)(bx + ty + r) * 768 + by + tx] = tile[tx][ty + r];
  }
}

// ---------------- 128x256 BK=32 TRIPLE-buffered bf16 MFMA GEMM ----------------
// C[m,n] = sum_k A[m,k]*W[n,k].  K=768 = 24 tiles of 32. 512 threads = 8 waves
// (2M x 4N). LDS 72 KiB (3 bufs) -> 2 blocks/CU. Prefetch distance 2 iters.
// modes: 0 fp32 plain
//        5 cat -> sel0: d0 k bf16 row-major | sel1: d1 v FRAG tiles
//                 sel2: d2 r sigmoid thread-tiles | sel3: d3 z bf16 row-major
__global__ __launch_bounds__(512, 4) void gemm_p(
    const ushort* __restrict__ A, const ushort* __restrict__ W,
    float* __restrict__ Cf,
    ushort* __restrict__ d0, ushort* __restrict__ d1,
    ushort* __restrict__ d2, ushort* __restrict__ d3, int mode) {
  __shared__ __align__(16) ushort lds[36864];  // A: 3x4096, B: 3x8192 (72 KiB)
  const int tid = threadIdx.x;
  const int wid = tid >> 6;
  const int lane = tid & 63;
  const int wr = wid >> 2, wc = wid & 3;
  const int fr = lane & 15, fq = lane >> 4;
  const int m0 = blockIdx.x * 128, n0 = blockIdx.y * 256;
  const int strow = tid >> 2;                        // 0..127
  const int stseg = (tid & 3) ^ ((strow >> 1) & 3);  // inverse-swizzled source seg
  const int rseg = fq ^ ((fr >> 1) & 3);             // swizzled read seg

  f32x4 acc[4][4];
#pragma unroll
  for (int m = 0; m < 4; ++m)
#pragma unroll
    for (int n = 0; n < 4; ++n) acc[m][n] = (f32x4){0.f, 0.f, 0.f, 0.f};

#define STAGE_T(kk0, b)                                                           \
  {                                                                               \
    const ushort* sa_ = A + (size_t)(m0 + strow) * 768 + (kk0) + stseg * 8;       \
    __builtin_amdgcn_global_load_lds(                                             \
        (const __attribute__((address_space(1))) void*)sa_,                       \
        (__attribute__((address_space(3))) void*)(lds + (b) * 4096 + tid * 8),    \
        16, 0, 0);                                                                \
    _Pragma("unroll") for (int j = 0; j < 2; ++j) {                               \
      const ushort* sb_ =                                                         \
          W + (size_t)(n0 + j * 128 + strow) * 768 + (kk0) + stseg * 8;           \
      __builtin_amdgcn_global_load_lds(                                           \
          (const __attribute__((address_space(1))) void*)sb_,                     \
          (__attribute__((address_space(3))) void*)(lds + 12288 + (b) * 8192 +    \
                                                    j * 4096 + tid * 8),          \
          16, 0, 0);                                                              \
    }                                                                             \
  }

  // prologue: tiles 0, 1, 2 -> bufs 0, 1, 2
  STAGE_T(0, 0);
  STAGE_T(32, 1);
  STAGE_T(64, 2);
  asm volatile("s_waitcnt vmcnt(6)" ::: "memory");  // tile 0 landed
  __builtin_amdgcn_s_barrier();

#pragma unroll 3
  for (int t = 0; t < 24; ++t) {
    const int buf = t % 3;
    bf16x8 aF[4], bF[4];
#pragma unroll
    for (int mi = 0; mi < 4; ++mi)
      aF[mi] = *reinterpret_cast<const bf16x8*>(
          lds + buf * 4096 + (wr * 64 + mi * 16 + fr) * 32 + rseg * 8);
#pragma unroll
    for (int nf = 0; nf < 4; ++nf)
      bF[nf] = *reinterpret_cast<const bf16x8*>(
          lds + 12288 + buf * 8192 + (wc * 64 + nf * 16 + fr) * 32 + rseg * 8);
    __builtin_amdgcn_s_setprio(1);
#pragma unroll
    for (int mi = 0; mi < 4; ++mi)
#pragma unroll
      for (int nf = 0; nf < 4; ++nf)
        acc[mi][nf] = __builtin_amdgcn_mfma_f32_16x16x32_bf16(
            aF[mi], bF[nf], acc[mi][nf], 0, 0, 0);
    __builtin_amdgcn_s_setprio(0);
    __builtin_amdgcn_s_barrier();           // all waves consumed buf
    if (t + 3 < 24) {
      STAGE_T((t + 3) * 32, buf);
      asm volatile("s_waitcnt vmcnt(6)" ::: "memory");  // tile t+1 landed
    } else if (t == 21) {
      asm volatile("s_waitcnt vmcnt(3)" ::: "memory");  // tile 22 landed
    } else if (t == 22) {
      asm volatile("s_waitcnt vmcnt(0)" ::: "memory");  // tile 23 landed
    }
    __builtin_amdgcn_s_barrier();
  }
#undef STAGE_T

  // ---- epilogue ----
  const int r0 = fq * 4;
  if (mode == 5) {
    const int sel = n0 >= 2304 ? 3 : n0 >= 1536 ? 2 : n0 >= 768 ? 1 : 0;
    const int nb = n0 - sel * 768;
    if (sel == 1) {
#pragma unroll
      for (int mf = 0; mf < 4; ++mf)
#pragma unroll
        for (int nf = 0; nf < 4; ++nf) {
          int gr = m0 + wr * 64 + mf * 16 + r0;
          int gc = nb + wc * 64 + nf * 16 + fr;
          int b = gr >> 11, t = gr & 2047;
          int c = t >> 6, s0 = t & 63;
          int h = gc >> 6, j = gc & 63;
          size_t addr = ((size_t)((b * 12 + h) * 32 + c)) * 4096 +
                        (size_t)(((j >> 4) * 2 + (s0 >> 5)) * 512 +
                                 (((s0 >> 3) & 3) * 16 + (j & 15)) * 8 + (s0 & 7));
          ushort4 o;
          o.x = f2bf(acc[mf][nf][0]); o.y = f2bf(acc[mf][nf][1]);
          o.z = f2bf(acc[mf][nf][2]); o.w = f2bf(acc[mf][nf][3]);
          *reinterpret_cast<ushort4*>(d1 + addr) = o;
        }
    } else if (sel == 2) {
#pragma unroll
      for (int mf = 0; mf < 4; ++mf)
#pragma unroll
        for (int nf = 0; nf < 4; ++nf) {
          int gr = m0 + wr * 64 + mf * 16 + r0;
          int gc = nb + wc * 64 + nf * 16 + fr;
          int b = gr >> 11, t = gr & 2047;
          int c = t >> 6, tin = t & 63;
          int h = gc >> 6, j = gc & 63;
          size_t addr = ((size_t)((b * 12 + h) * 32 + c)) * 4096 +
                        (size_t)(((tin >> 4) * 64 + ((tin >> 2) & 3) * 16 + (j & 15)) * 16 +
                                 (j >> 4) * 4);
          ushort4 o;
          o.x = f2bf(1.f / (1.f + __expf(-acc[mf][nf][0])));
          o.y = f2bf(1.f / (1.f + __expf(-acc[mf][nf][1])));
          o.z = f2bf(1.f / (1.f + __expf(-acc[mf][nf][2])));
          o.w = f2bf(1.f / (1.f + __expf(-acc[mf][nf][3])));
          *reinterpret_cast<ushort4*>(d2 + addr) = o;
        }
    } else {
      ushort* dst = sel == 0 ? d0 : d3;
#pragma unroll
      for (int mf = 0; mf < 4; ++mf)
#pragma unroll
        for (int nf = 0; nf < 4; ++nf) {
          int gr = m0 + wr * 64 + mf * 16 + r0;
          int gc = nb + wc * 64 + nf * 16 + fr;
#pragma unroll
          for (int rr = 0; rr < 4; ++rr)
            dst[(size_t)(gr + rr) * 768 + gc] = f2bf(acc[mf][nf][rr]);
        }
    }
  } else {
#pragma unroll
    for (int mf = 0; mf < 4; ++mf)
#pragma unroll
      for (int nf = 0; nf < 4; ++nf) {
        int gr = m0 + wr * 64 + mf * 16 + r0;
        int gc = n0 + wc * 64 + nf * 16 + fr;
#pragma unroll
        for (int rr = 0; rr < 4; ++rr)
          Cf[(size_t)(gr + rr) * 768 + gc] = acc[mf][nf][rr];
      }
  }
}

// ---------------- scan P: per (bh,c): cumprod + Mc = kIA^T V (parallel) ------
__global__ __launch_bounds__(256) void scan_mc3(
    const ushort* __restrict__ kb, const ushort* __restrict__ zb,
    const ushort* __restrict__ vbF, const float* __restrict__ bwp,
    ushort* __restrict__ McT, float* __restrict__ aend) {
  __shared__ ushort kt[64 * 72];
  __shared__ ushort zt[64 * 72];
  __shared__ ushort kIAfA[4096];
  __shared__ float part[256];
  const int bh = blockIdx.x, c = blockIdx.y;
  const int b = bh / H_, h = bh % H_;
  const int tid = threadIdx.x;
  const int w = tid >> 6, lane = tid & 63;
  const int fr = lane & 15, fq = lane >> 4;
  const int row = tid >> 2, c16 = (tid & 3) * 16;
  const float bwh = bwp[h * 64];

  {
    const ushort* gk = kb + ((size_t)(b * T_ + c * TC + row)) * 768 + h * 64 + c16;
    const ushort* gz = zb + ((size_t)(b * T_ + c * TC + row)) * 768 + h * 64 + c16;
    uint4 k0 = *(const uint4*)gk, k1 = *(const uint4*)(gk + 8);
    uint4 z0 = *(const uint4*)gz, z1 = *(const uint4*)(gz + 8);
    *reinterpret_cast<uint4*>(&kt[row * 72 + c16]) = k0;
    *reinterpret_cast<uint4*>(&kt[row * 72 + c16 + 8]) = k1;
    *reinterpret_cast<uint4*>(&zt[row * 72 + c16]) = z0;
    *reinterpret_cast<uint4*>(&zt[row * 72 + c16 + 8]) = z1;
  }
  bf16x8 vfr[8];
  {
    const ushort* vch = vbF + ((size_t)bh * NC + c) * 4096;
#pragma unroll
    for (int f = 0; f < 8; ++f)
      vfr[f] = *reinterpret_cast<const bf16x8*>(vch + f * 512 + lane * 8);
  }
  __syncthreads();
  float dreg[16];
  float p = 1.f;
#pragma unroll
  for (int tt = 0; tt < 16; ++tt) {
    float z = bf2f(zt[(w * 16 + tt) * 72 + lane]);
    float d = 1.f / (1.f + __expf(z + bwh));
    dreg[tt] = d;
    p *= d;
  }
  part[w * 64 + lane] = p;
  __syncthreads();
  float a = 1.f;
  for (int w2 = 0; w2 < w; ++w2) a *= part[w2 * 64 + lane];
  if (w == 0)
    aend[((size_t)bh * NC + c) * 64 + lane] =
        part[lane] * part[64 + lane] * part[128 + lane] * part[192 + lane];
#pragma unroll
  for (int tt = 0; tt < 16; ++tt) {
    int t = w * 16 + tt;
    float k = bf2f(kt[t * 72 + lane]);
    a *= dreg[tt];
    kIAfA[fragaddr(lane, t)] = f2bf(k / a);  // A-frag (m=i, k=s)
  }
  __syncthreads();

  bf16x8 af2[2];
#pragma unroll
  for (int kk = 0; kk < 2; ++kk)
    af2[kk] = *reinterpret_cast<const bf16x8*>(&kIAfA[(w * 2 + kk) * 512 + lane * 8]);
  f32x4 accM[4];
#pragma unroll
  for (int nf = 0; nf < 4; ++nf) accM[nf] = (f32x4){0.f, 0.f, 0.f, 0.f};
#pragma unroll
  for (int kk = 0; kk < 2; ++kk)
#pragma unroll
    for (int nf = 0; nf < 4; ++nf)
      accM[nf] = __builtin_amdgcn_mfma_f32_16x16x32_bf16(af2[kk], vfr[nf * 2 + kk], accM[nf], 0, 0, 0);
  ushort* mch = McT + ((size_t)bh * NC + c) * 4096;
#pragma unroll
  for (int nf = 0; nf < 4; ++nf) {
    ushort4 o;
    o.x = f2bf(accM[nf][0]); o.y = f2bf(accM[nf][1]);
    o.z = f2bf(accM[nf][2]); o.w = f2bf(accM[nf][3]);
    *reinterpret_cast<ushort4*>(&mch[(nf * 16 + fr) * 64 + w * 16 + fq * 4]) = o;
  }
}

// ---------------- scan C: chain, prefetch distance 2 (96x2 blocks) -----------
__global__ __launch_bounds__(256) void scan_chain3(
    const ushort* __restrict__ McT, const float* __restrict__ aend,
    ushort* __restrict__ S0F) {
  const int bh = blockIdx.x;
  const int j = threadIdx.x >> 2;
  const int i0 = blockIdx.y * 32 + (threadIdx.x & 3) * 8;
  const int fbase = ((j >> 4) * 2 + (i0 >> 5)) * 512 + (((i0 >> 3) & 3) * 16 + (j & 15)) * 8;
  const ushort* mbase = McT + ((size_t)bh * NC) * 4096 + j * 64 + i0;
  const float* abase = aend + ((size_t)bh * NC) * 64 + i0;
  float S[8];
#pragma unroll
  for (int p = 0; p < 8; ++p) S[p] = 0.f;

  // prologue: cur = chunk 0, next = chunk 1
  ushort4 m0 = *reinterpret_cast<const ushort4*>(mbase);
  ushort4 m1 = *reinterpret_cast<const ushort4*>(mbase + 4);
  float4 a0 = *(const float4*)(abase);
  float4 a1 = *(const float4*)(abase + 4);
  ushort4 n0 = *reinterpret_cast<const ushort4*>(mbase + 4096);
  ushort4 n1 = *reinterpret_cast<const ushort4*>(mbase + 4096 + 4);
  float4 b0 = *(const float4*)(abase + 64);
  float4 b1 = *(const float4*)(abase + 64 + 4);

  for (int c = 0; c < NC; ++c) {
    int cn2 = c + 2 < NC ? c + 2 : NC - 1;
    ushort4 p0 = *reinterpret_cast<const ushort4*>(mbase + (size_t)cn2 * 4096);
    ushort4 p1 = *reinterpret_cast<const ushort4*>(mbase + (size_t)cn2 * 4096 + 4);
    float4 q0 = *(const float4*)(abase + (size_t)cn2 * 64);
    float4 q1 = *(const float4*)(abase + (size_t)cn2 * 64 + 4);

    ushort* s0 = S0F + ((size_t)bh * NC + c) * 4096 + fbase;
    ushort4 o0, o1;
    o0.x = f2bf(S[0]); o0.y = f2bf(S[1]); o0.z = f2bf(S[2]); o0.w = f2bf(S[3]);
    o1.x = f2bf(S[4]); o1.y = f2bf(S[5]); o1.z = f2bf(S[6]); o1.w = f2bf(S[7]);
    *reinterpret_cast<ushort4*>(s0) = o0;
    *reinterpret_cast<ushort4*>(s0 + 4) = o1;

    S[0] = a0.x * (S[0] + bf2f(m0.x));
    S[1] = a0.y * (S[1] + bf2f(m0.y));
    S[2] = a0.z * (S[2] + bf2f(m0.z));
    S[3] = a0.w * (S[3] + bf2f(m0.w));
    S[4] = a1.x * (S[4] + bf2f(m1.x));
    S[5] = a1.y * (S[5] + bf2f(m1.y));
    S[6] = a1.z * (S[6] + bf2f(m1.z));
    S[7] = a1.w * (S[7] + bf2f(m1.w));

    m0 = n0; m1 = n1; a0 = b0; a1 = b1;
    n0 = p0; n1 = p1; b0 = q0; b1 = q1;
  }
}

// ---------------- scan Y: per (bh,c): A = causal(kA.kIA^T); y = kA.S0F + A.V --
__global__ __launch_bounds__(256, 2) void scan_y3(
    const ushort* __restrict__ kb, const ushort* __restrict__ zb,
    const ushort* __restrict__ vbF, const ushort* __restrict__ rbF,
    const ushort* __restrict__ S0F, const float* __restrict__ bwp,
    ushort* __restrict__ yrow) {
  __shared__ ushort kt[64 * 72];
  __shared__ ushort zt[64 * 72];
  __shared__ ushort kAf[4096];
  __shared__ ushort kIAfB[4096];
  __shared__ ushort Am[64 * 72];
  __shared__ float part[256];
  const int bh = blockIdx.x, c = blockIdx.y;
  const int b = bh / H_, h = bh % H_;
  const int tid = threadIdx.x;
  const int w = tid >> 6, lane = tid & 63;
  const int fr = lane & 15, fq = lane >> 4;
  const int row = tid >> 2, c16 = (tid & 3) * 16;
  const float bwh = bwp[h * 64];
  const int swz = fragswz(lane);

  {
    const ushort* gk = kb + ((size_t)(b * T_ + c * TC + row)) * 768 + h * 64 + c16;
    const ushort* gz = zb + ((size_t)(b * T_ + c * TC + row)) * 768 + h * 64 + c16;
    uint4 k0 = *(const uint4*)gk, k1 = *(const uint4*)(gk + 8);
    uint4 z0 = *(const uint4*)gz, z1 = *(const uint4*)(gz + 8);
    *reinterpret_cast<uint4*>(&kt[row * 72 + c16]) = k0;
    *reinterpret_cast<uint4*>(&kt[row * 72 + c16 + 8]) = k1;
    *reinterpret_cast<uint4*>(&zt[row * 72 + c16]) = z0;
    *reinterpret_cast<uint4*>(&zt[row * 72 + c16 + 8]) = z1;
  }
  bf16x8 vfr[8], s0fr[8];
  {
    const ushort* vch = vbF + ((size_t)bh * NC + c) * 4096;
    const ushort* s0ch = S0F + ((size_t)bh * NC + c) * 4096;
#pragma unroll
    for (int f = 0; f < 8; ++f) {
      vfr[f] = *reinterpret_cast<const bf16x8*>(vch + f * 512 + lane * 8);
      s0fr[f] = *reinterpret_cast<const bf16x8*>(s0ch + f * 512 + lane * 8);
    }
  }
  ushort4 rp0, rp1, rp2, rp3;
  {
    const ushort* rch = rbF + ((size_t)bh * NC + c) * 4096 + tid * 16;
    rp0 = *reinterpret_cast<const ushort4*>(rch);
    rp1 = *reinterpret_cast<const ushort4*>(rch + 4);
    rp2 = *reinterpret_cast<const ushort4*>(rch + 8);
    rp3 = *reinterpret_cast<const ushort4*>(rch + 12);
  }
  const ushort rl[16] = {rp0.x, rp0.y, rp0.z, rp0.w, rp1.x, rp1.y, rp1.z, rp1.w,
                         rp2.x, rp2.y, rp2.z, rp2.w, rp3.x, rp3.y, rp3.z, rp3.w};
  __syncthreads();
  float dreg[16];
  float p = 1.f;
#pragma unroll
  for (int tt = 0; tt < 16; ++tt) {
    float z = bf2f(zt[(w * 16 + tt) * 72 + lane]);
    float d = 1.f / (1.f + __expf(z + bwh));
    dreg[tt] = d;
    p *= d;
  }
  part[w * 64 + lane] = p;
  __syncthreads();
  float a = 1.f;
  for (int w2 = 0; w2 < w; ++w2) a *= part[w2 * 64 + lane];
#pragma unroll
  for (int tt = 0; tt < 16; ++tt) {
    int t = w * 16 + tt;
    float k = bf2f(kt[t * 72 + lane]);
    a *= dreg[tt];
    int ad = fragaddr(t, lane) ^ swz;
    kAf[ad] = f2bf(k * a);
    kIAfB[ad] = f2bf(k / a);
  }
  __syncthreads();

  bf16x8 af[2];
#pragma unroll
  for (int kk = 0; kk < 2; ++kk) {
    int ra = ((w * 2 + kk) * 512 + lane * 8) ^ (((lane >> 4) << 3) ^ (kk << 5));
    af[kk] = *reinterpret_cast<const bf16x8*>(&kAf[ra]);
  }
  {
    f32x4 accA[4];
#pragma unroll
    for (int nf = 0; nf < 4; ++nf) accA[nf] = (f32x4){0.f, 0.f, 0.f, 0.f};
#pragma unroll
    for (int kk = 0; kk < 2; ++kk)
#pragma unroll
      for (int nf = 0; nf < 4; ++nf) {
        int rb8 = ((nf * 2 + kk) * 512 + lane * 8) ^ (((lane >> 4) << 3) ^ (kk << 5));
        bf16x8 b8 = *reinterpret_cast<const bf16x8*>(&kIAfB[rb8]);
        accA[nf] = __builtin_amdgcn_mfma_f32_16x16x32_bf16(af[kk], b8, accA[nf], 0, 0, 0);
      }
#pragma unroll
    for (int nf = 0; nf < 4; ++nf)
#pragma unroll
      for (int q = 0; q < 4; ++q) {
        int t = w * 16 + fq * 4 + q;
        int s = nf * 16 + fr;
        Am[t * 72 + s] = f2bf((s <= t) ? accA[nf][q] : 0.f);
      }
  }
  __syncthreads();

  f32x4 accY[4];
#pragma unroll
  for (int nf = 0; nf < 4; ++nf) accY[nf] = (f32x4){0.f, 0.f, 0.f, 0.f};
#pragma unroll
  for (int kk = 0; kk < 2; ++kk)
#pragma unroll
    for (int nf = 0; nf < 4; ++nf)
      accY[nf] = __builtin_amdgcn_mfma_f32_16x16x32_bf16(af[kk], s0fr[nf * 2 + kk], accY[nf], 0, 0, 0);
#pragma unroll
  for (int kk = 0; kk < 2; ++kk) {
    bf16x8 am8 = *reinterpret_cast<const bf16x8*>(&Am[(w * 16 + fr) * 72 + kk * 32 + fq * 8]);
#pragma unroll
    for (int nf = 0; nf < 4; ++nf)
      accY[nf] = __builtin_amdgcn_mfma_f32_16x16x32_bf16(am8, vfr[nf * 2 + kk], accY[nf], 0, 0, 0);
  }
#pragma unroll
  for (int nf = 0; nf < 4; ++nf)
#pragma unroll
    for (int q = 0; q < 4; ++q) {
      int t = w * 16 + fq * 4 + q;
      int j = nf * 16 + fr;
      size_t go = ((size_t)(b * T_ + c * TC + t)) * 768 + h * 64 + j;
      yrow[go] = f2bf(accY[nf][q] * bf2f(rl[nf * 4 + q]));
    }
}

// ---------------- launch ----------------
extern "C" void kernel_launch(void* const* d_in, const int* in_sizes, int n_in,
                              void* d_out, int out_size, void* d_ws, size_t ws_size,
                              hipStream_t stream) {
  const float* x     = (const float*)d_in[0];
  const float* Wx    = (const float*)d_in[1];
  const float* Ww    = (const float*)d_in[2];
  const float* bw    = (const float*)d_in[3];
  const float* Wk    = (const float*)d_in[4];
  const float* Wv    = (const float*)d_in[5];
  const float* Wr    = (const float*)d_in[6];
  const float* Wo    = (const float*)d_in[7];
  const float* gamma = (const float*)d_in[8];
  const float* beta  = (const float*)d_in[9];
  float* out = (float*)d_out;

  // workspace (bytes), NEED proven rounds 3-18:
  //   xn   [0,          25165824)  bf16 xn -> McT (after cat)
  //   wb   [25165824,   32243712)  6 slots: Wk,Wv,Wr,M,Wo,Ww
  //   WxT  [32243712,   57409536)  WxT (dead after M-gemm) -> S0F
  //   kb   [57409536,   82575360)
  //   vbF  [82575360,  107741184)  v fragment tiles per (bh,c)
  //   rbF  [107741184, 132907008)  r thread-ordered tiles per (bh,c)
  //   yr   [132907008, 158072832)  head = aend fp32 (dead before scan_y3 writes)
  //   zb   [158072832, 183238656)  bf16 z
  const size_t NEED = 208404480ull;
  if (ws_size < NEED) {
    zero_out_kernel<<<2048, 256, 0, stream>>>(out, out_size);
    return;
  }

  char* ws = (char*)d_ws;
  ushort* xn  = (ushort*)ws;
  ushort* wb  = (ushort*)(ws + 25165824);
  ushort* WxT = (ushort*)(ws + 32243712);
  ushort* kb  = (ushort*)(ws + 57409536);
  ushort* vbF = (ushort*)(ws + 82575360);
  ushort* rbF = (ushort*)(ws + 107741184);
  ushort* yr  = (ushort*)(ws + 132907008);
  ushort* zb  = (ushort*)(ws + 158072832);
  ushort* McT = (ushort*)ws;                 // aliases xn (dead after cat)
  ushort* S0F = (ushort*)(ws + 32243712);    // aliases WxT (dead after M-gemm)
  float*  aendb = (float*)(ws + 132907008);  // yr head (dead before scan_y3)

  ushort* WcatB = wb;                 // slots 0..3: Wk, Wv, Wr, M
  ushort* Mb  = wb + 3 * 589824;
  ushort* WoB = wb + 4 * 589824;
  ushort* WwB = wb + 5 * 589824;

  // fused prep (5 casts + WxT transpose) + LayerNorm
  prepln_kernel<<<5248, 256, 0, stream>>>(x, gamma, beta, xn,
                                          Wk, Wv, Wr, Wo, Ww, Wx, wb, WxT);
  // composite M = Ww @ Wx
  gemm_p<<<dim3(6, 3), 512, 0, stream>>>(WwB, WxT, nullptr, Mb, nullptr, nullptr,
                                         nullptr, 5);
  // fused k/v/r/z GEMM (N=3072): k bf16, v frag, r thread-tiles sigmoid, z bf16
  gemm_p<<<dim3(128, 12), 512, 0, stream>>>(xn, WcatB, nullptr, kb, vbF, rbF, zb, 5);

  scan_mc3<<<dim3(96, NC), 256, 0, stream>>>(kb, zb, vbF, bw, McT, aendb);
  scan_chain3<<<dim3(96, 2), 256, 0, stream>>>(McT, aendb, S0F);
  scan_y3<<<dim3(96, NC), 256, 0, stream>>>(kb, zb, vbF, rbF, S0F, bw, yr);

  // final GEMM (N=768): fp32 out
  gemm_p<<<dim3(128, 3), 512, 0, stream>>>(yr, WoB, out, nullptr, nullptr, nullptr,
                                           nullptr, 0);
}